// Round 9
// baseline (126.371 us; speedup 1.0000x reference)
//
#include <hip/hip_runtime.h>

// NeRF fused kernel for MI355X (gfx950) — round 9.
// Round 8 post-mortem: 51.8 us but cycle ledger shows ~8.6k of ~11.6k cycles
// per block-lifetime are startup/drain (kernarg loads, cold weight frags,
// I$ cold-fetch of a once-executed unrolled body, po/pd latency, tail) —
// MfmaUtil 29 / VALU 53 / rest idle. Fix: PERSISTENT blocks. Grid = 768
// (256 CU x 3 resident, reg-capped occupancy), each block grid-strides over
// ~10.7 ray-pairs. All loop-invariants hoisted to regs once per block:
// W2 slice frags (32 VGPR), W3, b2, b3, W1 strip, m2. Loop body is I$-hot
// from iter 2; per-iter global traffic = 2 rays' origins+dirs only.
// Structure otherwise = r8 (verified absmax 16): block = 2 rays/iter,
// wave w = h2-feature slice [32w,32w+32) for all 128 points; permutation
// hand-off phase2 acc -> phase3 B-frags; cross-wave f reduction in LDS.

typedef _Float16 f16;
typedef __attribute__((ext_vector_type(2))) _Float16 h2v;
typedef __attribute__((ext_vector_type(8))) _Float16 half8;
typedef __attribute__((ext_vector_type(4))) float floatx4;

#define H 128
#define NS 64
#define NBLK 768
#define RAYPAIRS 8192

static __device__ __forceinline__ h2v pkrtz(float a, float b) {
  return __builtin_bit_cast(h2v, __builtin_amdgcn_cvt_pkrtz(a, b));
}

// ---------------------------------------------------------------------------
// Setup (identical to round 8, HW-verified). W2 -> A-frags per (wv, ks, mtl):
//   elem j at lane = W2[k][n], k = ks*32 + (lane>>4)*8 + j,
//   n = 32*wv + ((lane&15)>>2)*8 + mtl*4 + (lane&3).
// W3 -> A-frags per slice wv (cols padded to 16):
//   elem j at lane = W3[32*wv + (lane>>4)*8 + j][lane&15]  (0 if col>=4).
// b2 -> natural-order f16.
// ---------------------------------------------------------------------------
__global__ void nerf_setup(const float* __restrict__ W2, const float* __restrict__ W3,
                           const float* __restrict__ b2,
                           f16* __restrict__ wsW2, f16* __restrict__ wsW3,
                           f16* __restrict__ wsB2) {
  int t = blockIdx.x * blockDim.x + threadIdx.x;
  if (t < 8192) {                       // W2 frags: 32 frags x 64 lanes x 4 dwords
    int j2 = t & 3, lane = (t >> 2) & 63, fid = t >> 8;   // fid 0..31
    int mtl = fid & 1, ks = (fid >> 1) & 3, wv = fid >> 3;
    int l16 = lane & 15;
    int k = ks * 32 + ((lane >> 4) * 8) + 2 * j2;
    int n = 32 * wv + (l16 >> 2) * 8 + mtl * 4 + (l16 & 3);
    wsW2[2 * t]     = (f16)W2[k * H + n];
    wsW2[2 * t + 1] = (f16)W2[(k + 1) * H + n];
  } else if (t < 9216) {                // W3 frags: 4 slices x 64 lanes x 4 dwords
    int u = t - 8192;
    int j2 = u & 3, lane = (u >> 2) & 63, wv = u >> 8;
    int c = lane & 15;
    int k3 = 32 * wv + ((lane >> 4) * 8) + 2 * j2;
    wsW3[2 * u]     = (c < 4) ? (f16)W3[k3 * 4 + c]       : (f16)0.0f;
    wsW3[2 * u + 1] = (c < 4) ? (f16)W3[(k3 + 1) * 4 + c] : (f16)0.0f;
  } else if (t < 9344) {                // b2, natural order f16
    int i = t - 9216;
    wsB2[i] = (f16)b2[i];
  }
}

// ---------------------------------------------------------------------------
// Main: persistent. Block iterates ray-pairs p = blockIdx.x + k*gridDim.x.
// Per iter: block = 2 rays = 128 points; wave w = feature slice [32w,32w+32).
// ---------------------------------------------------------------------------
__global__ __launch_bounds__(256, 3) void nerf_main(
    const float* __restrict__ origins, const float* __restrict__ dirs,
    const float* __restrict__ W1, const float* __restrict__ b1,
    const float* __restrict__ b3,
    const f16* __restrict__ wsW2, const f16* __restrict__ wsW3,
    const f16* __restrict__ wsB2,
    float* __restrict__ out)
{
  __shared__ __align__(16) f16   popd[2][2][H];    // [ray][po|pd][k]  (1 KB)
  __shared__ __align__(16) float f_lds[4][128][4]; // partial f per wave (8 KB)

  const int t = threadIdx.x;
  const int w = t >> 6, lane = t & 63, quad = lane >> 4, l16 = lane & 15;
  const float delta = 4.0f / NS;       // near=2, far=6 baked

  // ==== Loop-invariant state, loaded ONCE per block ====
  // This wave's W2 slice (8 KB -> 32 VGPR), W3 slice, b2 slice, b3.
  const half8* w2f = (const half8*)wsW2;
  half8 aw[4][2];
  #pragma unroll
  for (int ks = 0; ks < 4; ++ks)
    #pragma unroll
    for (int mtl = 0; mtl < 2; ++mtl)
      aw[ks][mtl] = w2f[((w * 4 + ks) * 2 + mtl) * 64 + lane];
  const half8 w3 = ((const half8*)wsW3)[w * 64 + lane];
  h2v bk[4];
  {
    uint4 u = *(const uint4*)(wsB2 + 32 * w + quad * 8);   // feats 32w+8q..+7
    bk[0] = __builtin_bit_cast(h2v, u.x);
    bk[1] = __builtin_bit_cast(h2v, u.y);
    bk[2] = __builtin_bit_cast(h2v, u.z);
    bk[3] = __builtin_bit_cast(h2v, u.w);
  }
  const float4 b3v = *(const float4*)b3;
  // W1 strip + b1 (per-lane cols 2*lane, 2*lane+1) — used by waves 0,1.
  const int k0 = lane * 2;
  const float2 wr0 = *(const float2*)&W1[0*H + k0];
  const float2 wr1 = *(const float2*)&W1[1*H + k0];
  const float2 wr2 = *(const float2*)&W1[2*H + k0];
  const float2 bb  = *(const float2*)&b1[k0];
  // m pairs per ntile: point = nt*16 + l16; sample within ray = (nt&3)*16+l16
  h2v m2[8];
  #pragma unroll
  for (int nt = 0; nt < 8; ++nt) {
    const f16 m = (f16)(2.0f + ((nt & 3) * 16 + l16 + 0.5f) * delta);
    m2[nt][0] = m; m2[nt][1] = m;
  }
  const h2v z2 = (h2v)(f16)0.0f;

  // ==== Persistent loop over ray-pairs ====
  for (int p = blockIdx.x; p < RAYPAIRS; p += NBLK) {
    // ---- po/pd: waves 0,1 for rays 2p, 2p+1 ----
    if (w < 2) {
      const int ray = 2 * p + w;
      const float o0 = origins[ray*3], o1 = origins[ray*3+1], o2 = origins[ray*3+2];
      const float d0 = dirs[ray*3],    d1 = dirs[ray*3+1],    d2 = dirs[ray*3+2];
      float poa = fmaf(o2, wr2.x, fmaf(o1, wr1.x, fmaf(o0, wr0.x, bb.x)));
      float pob = fmaf(o2, wr2.y, fmaf(o1, wr1.y, fmaf(o0, wr0.y, bb.y)));
      float pda = fmaf(d2, wr2.x, fmaf(d1, wr1.x, d0 * wr0.x));
      float pdb = fmaf(d2, wr2.y, fmaf(d1, wr1.y, d0 * wr0.y));
      h2v po2; po2[0] = (f16)poa; po2[1] = (f16)pob;
      h2v pd2; pd2[0] = (f16)pda; pd2[1] = (f16)pdb;
      *(h2v*)&popd[w][0][k0] = po2;
      *(h2v*)&popd[w][1][k0] = pd2;
    }
    __syncthreads();

    // ---- Phase 2: slice of h2'^T; 4 ks x 8 nt x 2 mtl MFMAs ----
    floatx4 acc[2][8];
    #pragma unroll
    for (int nt = 0; nt < 8; ++nt) { acc[0][nt] = (floatx4)(0.0f); acc[1][nt] = (floatx4)(0.0f); }

    #pragma unroll
    for (int ks = 0; ks < 4; ++ks) {
      const half8 poA = *(const half8*)&popd[0][0][ks*32 + quad*8];
      const half8 pdA = *(const half8*)&popd[0][1][ks*32 + quad*8];
      #pragma unroll
      for (int nt = 0; nt < 4; ++nt) {
        union { half8 v; h2v p[4]; } P, O, Hb;
        P.v = pdA; O.v = poA;
        #pragma unroll
        for (int p2 = 0; p2 < 4; ++p2)
          Hb.p[p2] = __builtin_elementwise_max((h2v)(P.p[p2] * m2[nt] + O.p[p2]), z2);
        acc[0][nt] = __builtin_amdgcn_mfma_f32_16x16x32_f16(aw[ks][0], Hb.v, acc[0][nt], 0, 0, 0);
        acc[1][nt] = __builtin_amdgcn_mfma_f32_16x16x32_f16(aw[ks][1], Hb.v, acc[1][nt], 0, 0, 0);
      }
      const half8 poB = *(const half8*)&popd[1][0][ks*32 + quad*8];
      const half8 pdB = *(const half8*)&popd[1][1][ks*32 + quad*8];
      #pragma unroll
      for (int nt = 4; nt < 8; ++nt) {
        union { half8 v; h2v p[4]; } P, O, Hb;
        P.v = pdB; O.v = poB;
        #pragma unroll
        for (int p2 = 0; p2 < 4; ++p2)
          Hb.p[p2] = __builtin_elementwise_max((h2v)(P.p[p2] * m2[nt] + O.p[p2]), z2);
        acc[0][nt] = __builtin_amdgcn_mfma_f32_16x16x32_f16(aw[ks][0], Hb.v, acc[0][nt], 0, 0, 0);
        acc[1][nt] = __builtin_amdgcn_mfma_f32_16x16x32_f16(aw[ks][1], Hb.v, acc[1][nt], 0, 0, 0);
      }
    }

    // ---- Phase 3: partial f^T via slice W3; B-frags straight from acc ----
    #pragma unroll
    for (int nt = 0; nt < 8; ++nt) {
      h2v c0 = __builtin_elementwise_max((h2v)(pkrtz(acc[0][nt][0], acc[0][nt][1]) + bk[0]), z2);
      h2v c1 = __builtin_elementwise_max((h2v)(pkrtz(acc[0][nt][2], acc[0][nt][3]) + bk[1]), z2);
      h2v c2 = __builtin_elementwise_max((h2v)(pkrtz(acc[1][nt][0], acc[1][nt][1]) + bk[2]), z2);
      h2v c3 = __builtin_elementwise_max((h2v)(pkrtz(acc[1][nt][2], acc[1][nt][3]) + bk[3]), z2);
      half8 b = { c0[0], c0[1], c1[0], c1[1], c2[0], c2[1], c3[0], c3[1] };
      floatx4 d = __builtin_amdgcn_mfma_f32_16x16x32_f16(w3, b, (floatx4)(0.0f), 0, 0, 0);
      if (quad == 0) {                  // rows 0..3 = (R,G,B,sigma) partials
        float4 fv; fv.x = d[0]; fv.y = d[1]; fv.z = d[2]; fv.w = d[3];
        *(float4*)&f_lds[w][nt*16 + l16][0] = fv;
      }
    }
    __syncthreads();

    // ---- Phase 4: reduce 4 partials + b3; waves 0,1 render rays 2p,2p+1 ----
    if (w < 2) {
      const int pt = w * 64 + lane;
      const float4 s0 = *(const float4*)&f_lds[0][pt][0];
      const float4 s1 = *(const float4*)&f_lds[1][pt][0];
      const float4 s2 = *(const float4*)&f_lds[2][pt][0];
      const float4 s3 = *(const float4*)&f_lds[3][pt][0];
      const float fr = s0.x + s1.x + s2.x + s3.x + b3v.x;
      const float fg = s0.y + s1.y + s2.y + s3.y + b3v.y;
      const float fb = s0.z + s1.z + s2.z + s3.z + b3v.z;
      const float sigma = s0.w + s1.w + s2.w + s3.w + b3v.w;

      const float alpha = 1.0f - __expf(-sigma * delta);
      float S = sigma;
      #pragma unroll
      for (int off = 1; off < 64; off <<= 1) {
        float u = __shfl_up(S, off);
        if (lane >= off) S += u;
      }
      const float T  = __expf(-delta * (S - sigma));   // exclusive prefix
      const float wt = alpha * T;
      float cr = wt * fr, cg = wt * fg, cb = wt * fb;
      #pragma unroll
      for (int off = 32; off > 0; off >>= 1) {
        cr += __shfl_down(cr, off);
        cg += __shfl_down(cg, off);
        cb += __shfl_down(cb, off);
      }
      if (lane == 0) {
        const int ray = 2 * p + w;
        out[ray*3+0] = cr; out[ray*3+1] = cg; out[ray*3+2] = cb;
      }
    }
    // Hazards across iterations: barrier 2 (above) separates this iter's
    // phase-2 popd reads from next iter's popd writes; waves 2,3 cannot pass
    // next iter's barrier 1 until waves 0,1 finish rendering (f_lds safe).
  }
}

extern "C" void kernel_launch(void* const* d_in, const int* in_sizes, int n_in,
                              void* d_out, int out_size, void* d_ws, size_t ws_size,
                              hipStream_t stream) {
  const float* origins = (const float*)d_in[0];
  const float* dirs    = (const float*)d_in[1];
  const float* W1      = (const float*)d_in[2];
  const float* b1      = (const float*)d_in[3];
  const float* W2      = (const float*)d_in[4];
  const float* b2      = (const float*)d_in[5];
  const float* W3      = (const float*)d_in[6];
  const float* b3      = (const float*)d_in[7];
  float* out = (float*)d_out;

  f16* wsW2 = (f16*)d_ws;          // 16384 f16 = 32 KB
  f16* wsW3 = wsW2 + 16384;        // 2048 f16  = 4 KB
  f16* wsB2 = wsW3 + 2048;         // 128 f16   = 256 B

  nerf_setup<<<37, 256, 0, stream>>>(W2, W3, b2, wsW2, wsW3, wsB2);
  nerf_main<<<NBLK, 256, 0, stream>>>(
      origins, dirs, W1, b1, b3, wsW2, wsW3, wsB2, out);
}

// Round 10
// 108.140 us; speedup vs baseline: 1.1686x; 1.1686x over previous
//
#include <hip/hip_runtime.h>

// NeRF fused kernel for MI355X (gfx950) — round 10.
// History: r6 (42.0 us, block=4 rays, wave=1 ray, zero barriers, MfmaUtil 35%)
// is the best structure. r7 (point-split, 3 waves/SIMD) and r9 (persistent)
// both regressed: the idle is intra-block serial LOAD LATENCY, not startup.
// r6's K-loop pulls 32 KB of W2 frags per wave through VMEM (global b128,
// ~200-900 cy) — 536 MB L2 traffic, latency uncoverable at 2 waves/SIMD.
// Fix: stage W2 frags into LDS ONCE per block (coalesced, one barrier), read
// frags via ds_read_b128 (~120 cy, conflict-free). Everything else = r6
// (verified absmax 16): h2-feature permutation makes phase-2 D regs ==
// phase-3 B frags (zero h2 LDS); fused bias+relu+pack epilogue; per-wave
// rendering with shfl prefix-sum.

typedef _Float16 f16;
typedef __attribute__((ext_vector_type(2))) _Float16 h2v;
typedef __attribute__((ext_vector_type(8))) _Float16 half8;
typedef __attribute__((ext_vector_type(4))) float floatx4;

#define H 128
#define NS 64

static __device__ __forceinline__ h2v pkrtz(float a, float b) {
  return __builtin_bit_cast(h2v, __builtin_amdgcn_cvt_pkrtz(a, b));
}

// ---------------------------------------------------------------------------
// Setup (identical to rounds 5/6, HW-verified): W2 -> A-frags with permuted
// h2 columns n = 32*(l16>>2) + mt*4 + (l16&3); W3 -> A-frags with matching
// permuted rows k3 = 32*(lane>>4) + ks*8 + j (cols padded to 16); b2 natural.
// ---------------------------------------------------------------------------
__global__ void nerf_setup(const float* __restrict__ W2, const float* __restrict__ W3,
                           const float* __restrict__ b2,
                           f16* __restrict__ wsW2, f16* __restrict__ wsW3,
                           f16* __restrict__ wsB2) {
  int t = blockIdx.x * blockDim.x + threadIdx.x;
  if (t < 8192) {                       // W2 frags
    int j2 = t & 3, lane = (t >> 2) & 63, mt = (t >> 8) & 7, ks = t >> 11;
    int l16 = lane & 15;
    int k = ks * 32 + ((lane >> 4) * 8) + 2 * j2;
    int n = 32 * (l16 >> 2) + mt * 4 + (l16 & 3);    // permuted column
    wsW2[2 * t]     = (f16)W2[k * H + n];
    wsW2[2 * t + 1] = (f16)W2[(k + 1) * H + n];
  } else if (t < 9216) {                // W3 frags (A-layout, permuted rows, padded)
    int u = t - 8192;
    int j2 = u & 3, lane = (u >> 2) & 63, ks = u >> 8;
    int c = lane & 15;
    int k3 = 32 * (lane >> 4) + ks * 8 + 2 * j2;     // permuted h2 feature
    wsW3[2 * u]     = (c < 4) ? (f16)W3[k3 * 4 + c]       : (f16)0.0f;
    wsW3[2 * u + 1] = (c < 4) ? (f16)W3[(k3 + 1) * 4 + c] : (f16)0.0f;
  } else if (t < 9344) {                // b2, natural order f16
    int i = t - 9216;
    wsB2[i] = (f16)b2[i];
  }
}

// ---------------------------------------------------------------------------
// Main: block = 4 rays = 4 waves; wave = 1 ray = 64 points; one barrier
// (W2 LDS staging). popd/f_lds are same-wave (no barrier needed for them).
// ---------------------------------------------------------------------------
__global__ __launch_bounds__(256, 2) void nerf_main(
    const float* __restrict__ origins, const float* __restrict__ dirs,
    const float* __restrict__ W1, const float* __restrict__ b1,
    const float* __restrict__ b3,
    const f16* __restrict__ wsW2, const f16* __restrict__ wsW3,
    const f16* __restrict__ wsB2,
    float* __restrict__ out)
{
  __shared__ __align__(16) f16   w2s[16384];      // staged W2 frags (32 KB)
  __shared__ __align__(16) f16   popd[4][2][H];   // per-wave po/pd strips (2 KB)
  __shared__ __align__(16) float f_lds[4][64][4]; // render transpose (4 KB)

  const int t = threadIdx.x;
  const int w = t >> 6, lane = t & 63, quad = lane >> 4, l16 = lane & 15;
  const float delta = 4.0f / NS;       // near=2, far=6 baked
  const int ray = blockIdx.x * 4 + w;

  // ---- Issue all global loads early (latency overlaps staging+po/pd) ----
  const float o0 = origins[ray*3], o1 = origins[ray*3+1], o2 = origins[ray*3+2];
  const float d0 = dirs[ray*3],    d1 = dirs[ray*3+1],    d2 = dirs[ray*3+2];
  const int k0 = lane * 2;
  const float2 wr0 = *(const float2*)&W1[0*H + k0];
  const float2 wr1 = *(const float2*)&W1[1*H + k0];
  const float2 wr2 = *(const float2*)&W1[2*H + k0];
  const float2 bb  = *(const float2*)&b1[k0];
  const half8* w3f = (const half8*)wsW3;
  half8 w3[4];
  #pragma unroll
  for (int ks = 0; ks < 4; ++ks) w3[ks] = w3f[ks*64 + lane];
  h2v bk0[8], bk1[8];
  {
    const uint2* bp = (const uint2*)wsB2;
    #pragma unroll
    for (int mt = 0; mt < 8; ++mt) {
      uint2 u = bp[quad * 8 + mt];                   // b2[32q+4mt .. +3]
      bk0[mt] = __builtin_bit_cast(h2v, u.x);
      bk1[mt] = __builtin_bit_cast(h2v, u.y);
    }
  }
  const float4 b3v = *(const float4*)b3;

  // ---- Stage W2 frag table into LDS (32 KB, coalesced 16B chunks) ----
  {
    const uint4* src = (const uint4*)wsW2;
    uint4* dst = (uint4*)w2s;
    #pragma unroll
    for (int c = 0; c < 8; ++c)
      dst[t + c * 256] = src[t + c * 256];
  }

  // ---- po/pd: po[k] = o@W1[:,k]+b1[k], pd[k] = d@W1[:,k]; f16 to LDS ----
  {
    float poa = fmaf(o2, wr2.x, fmaf(o1, wr1.x, fmaf(o0, wr0.x, bb.x)));
    float pob = fmaf(o2, wr2.y, fmaf(o1, wr1.y, fmaf(o0, wr0.y, bb.y)));
    float pda = fmaf(d2, wr2.x, fmaf(d1, wr1.x, d0 * wr0.x));
    float pdb = fmaf(d2, wr2.y, fmaf(d1, wr1.y, d0 * wr0.y));
    h2v po2; po2[0] = (f16)poa; po2[1] = (f16)pob;
    h2v pd2; pd2[0] = (f16)pda; pd2[1] = (f16)pdb;
    *(h2v*)&popd[w][0][k0] = po2;
    *(h2v*)&popd[w][1][k0] = pd2;
  }
  __syncthreads();   // staging complete (popd is same-wave, but barrier is here anyway)

  // m splats per n-tile: sample s = tr*16 + l16; m exact in f16 (mult of 1/32)
  half8 m8[4];
  #pragma unroll
  for (int tr = 0; tr < 4; ++tr)
    m8[tr] = (half8)(f16)(2.0f + (tr*16 + l16 + 0.5f) * delta);

  // ---- Phase 2: h2'^T = W2'^T @ h1^T, 4 ks x 4 tr x 8 mt MFMAs.
  // Frags from LDS: frag f at w2s[f*512 + lane*8] (16B stride, conflict-free).
  floatx4 acc[8][4];
  #pragma unroll
  for (int mt = 0; mt < 8; ++mt)
    #pragma unroll
    for (int tr = 0; tr < 4; ++tr) acc[mt][tr] = (floatx4)(0.0f);

  const half8 z8 = (half8)(f16)0.0f;
  half8 awA[8], awB[8];
  #pragma unroll
  for (int mt = 0; mt < 8; ++mt)
    awA[mt] = *(const half8*)&w2s[mt*512 + lane*8];          // ks=0 prefetch

  #pragma unroll
  for (int ks = 0; ks < 4; ++ks) {
    half8* cur = (ks & 1) ? awB : awA;
    half8* nxt = (ks & 1) ? awA : awB;
    if (ks < 3) {
      #pragma unroll
      for (int mt = 0; mt < 8; ++mt)
        nxt[mt] = *(const half8*)&w2s[((ks+1)*8 + mt)*512 + lane*8];
    }
    const half8 po8 = *(const half8*)&popd[w][0][ks*32 + quad*8];
    const half8 pd8 = *(const half8*)&popd[w][1][ks*32 + quad*8];
    #pragma unroll
    for (int tr = 0; tr < 4; ++tr) {
      half8 hb = pd8 * m8[tr] + po8;                 // v_pk_fma_f16 x4
      hb = __builtin_elementwise_max(hb, z8);        // v_pk_max_f16 x4
      #pragma unroll
      for (int mt = 0; mt < 8; ++mt)
        acc[mt][tr] = __builtin_amdgcn_mfma_f32_16x16x32_f16(cur[mt], hb, acc[mt][tr], 0, 0, 0);
    }
  }

  // ---- Phase 3 (fused epilogue): f^T = W3'^T @ h2'^T. B-frags straight from
  // acc registers (permutation hand-off), bias+relu+pack on the fly. ----
  const h2v z2 = (h2v)(f16)0.0f;
  floatx4 acc3[4];
  #pragma unroll
  for (int tr = 0; tr < 4; ++tr) {
    acc3[tr] = (floatx4)(0.0f);
    #pragma unroll
    for (int ks = 0; ks < 4; ++ks) {
      const int mt0 = 2*ks, mt1 = 2*ks + 1;
      h2v c0 = __builtin_elementwise_max((h2v)(pkrtz(acc[mt0][tr][0], acc[mt0][tr][1]) + bk0[mt0]), z2);
      h2v c1 = __builtin_elementwise_max((h2v)(pkrtz(acc[mt0][tr][2], acc[mt0][tr][3]) + bk1[mt0]), z2);
      h2v c2 = __builtin_elementwise_max((h2v)(pkrtz(acc[mt1][tr][0], acc[mt1][tr][1]) + bk0[mt1]), z2);
      h2v c3 = __builtin_elementwise_max((h2v)(pkrtz(acc[mt1][tr][2], acc[mt1][tr][3]) + bk1[mt1]), z2);
      half8 b = { c0[0], c0[1], c1[0], c1[1], c2[0], c2[1], c3[0], c3[1] };
      acc3[tr] = __builtin_amdgcn_mfma_f32_16x16x32_f16(w3[ks], b, acc3[tr], 0, 0, 0);
    }
  }

  // D3: lane holds f[m = quad*4+r][point tr*16+l16]; quad 0 rows = (R,G,B,sigma).
  if (quad == 0) {
    #pragma unroll
    for (int tr = 0; tr < 4; ++tr) {
      float4 fv;
      fv.x = acc3[tr][0] + b3v.x;
      fv.y = acc3[tr][1] + b3v.y;
      fv.z = acc3[tr][2] + b3v.z;
      fv.w = acc3[tr][3] + b3v.w;
      *(float4*)&f_lds[w][tr*16 + l16][0] = fv;      // ds_write_b128
    }
  }
  // No barrier: same wave wrote these rows.

  // ---- Phase 4: volume rendering, wave renders its own ray, lane = sample ----
  {
    const float4 fv = *(const float4*)&f_lds[w][lane][0];
    const float sigma = fv.w;
    const float alpha = 1.0f - __expf(-sigma * delta);
    float S = sigma;
    #pragma unroll
    for (int off = 1; off < 64; off <<= 1) {
      float u = __shfl_up(S, off);
      if (lane >= off) S += u;
    }
    const float T  = __expf(-delta * (S - sigma));   // exclusive prefix
    const float wt = alpha * T;
    float cr = wt * fv.x, cg = wt * fv.y, cb = wt * fv.z;
    #pragma unroll
    for (int off = 32; off > 0; off >>= 1) {
      cr += __shfl_down(cr, off);
      cg += __shfl_down(cg, off);
      cb += __shfl_down(cb, off);
    }
    if (lane == 0) {
      out[ray*3+0] = cr; out[ray*3+1] = cg; out[ray*3+2] = cb;
    }
  }
}

extern "C" void kernel_launch(void* const* d_in, const int* in_sizes, int n_in,
                              void* d_out, int out_size, void* d_ws, size_t ws_size,
                              hipStream_t stream) {
  const float* origins = (const float*)d_in[0];
  const float* dirs    = (const float*)d_in[1];
  const float* W1      = (const float*)d_in[2];
  const float* b1      = (const float*)d_in[3];
  const float* W2      = (const float*)d_in[4];
  const float* b2      = (const float*)d_in[5];
  const float* W3      = (const float*)d_in[6];
  const float* b3      = (const float*)d_in[7];
  float* out = (float*)d_out;

  f16* wsW2 = (f16*)d_ws;          // 16384 f16 = 32 KB
  f16* wsW3 = wsW2 + 16384;        // 2048 f16  = 4 KB
  f16* wsB2 = wsW3 + 2048;         // 128 f16   = 256 B

  nerf_setup<<<37, 256, 0, stream>>>(W2, W3, b2, wsW2, wsW3, wsB2);
  nerf_main<<<16384 / 4, 256, 0, stream>>>(
      origins, dirs, W1, b1, b3, wsW2, wsW3, wsB2, out);
}